// Round 3
// baseline (2826.047 us; speedup 1.0000x reference)
//
#include <hip/hip_runtime.h>

#define D_DIM 1024
#define B_ROWS 65536

typedef unsigned short u16;
typedef __attribute__((ext_vector_type(4))) __bf16 bf16x4;
typedef __attribute__((ext_vector_type(8))) __bf16 bf16x8;
typedef __attribute__((ext_vector_type(4))) float f32x4;

typedef const __attribute__((address_space(1))) void* gas_cptr;
typedef __attribute__((address_space(3))) void* las_ptr;

__device__ __forceinline__ u16 f2bf(float f) {
  union { float fv; unsigned int i; } v; v.fv = f;
  return (u16)((v.i + 0x7FFFu + ((v.i >> 16) & 1u)) >> 16);
}

// C = A(f32) * W(bf16)^T (+bias[col]) (+R f32).
// 128x128 tile, BK=64, 4 waves (2x2), double-buffered LDS, XOR-swizzled tiles.
// A: reg-staged (f32->bf16 cvt at stage, swizzled ds_write).
// B: global_load_lds w16, inverse-swizzled global source, swizzled read.
#define BM 128
#define BN 128
#define BK 64
#define ABUF (128 * 64)  // u16 elems per buffer
#define BBUF (128 * 64)

template <int OUT_BF16>
__global__ __launch_bounds__(256, 2) void gemm_af32_bt(
    const float* __restrict__ A, const u16* __restrict__ W,
    const float* __restrict__ bias, const float* R, void* Optr,
    int M, int N, int K)
{
  __shared__ __align__(16) u16 sA[2 * ABUF];  // 32 KB
  __shared__ __align__(16) u16 sB[2 * BBUF];  // 32 KB

  // XCD-aware bijective swizzle (nwg % 8 == 0 for all our launches)
  const int nbx = gridDim.x;
  const int nwg = nbx * gridDim.y;
  const int orig = blockIdx.y * nbx + blockIdx.x;
  const int cpx = nwg >> 3;
  const int swz = ((nwg & 7) == 0) ? ((orig & 7) * cpx + (orig >> 3)) : orig;
  const int bm = swz / nbx, bn = swz % nbx;

  const int tid = threadIdx.x;
  const int wave = tid >> 6;
  const int lane = tid & 63;
  const int wr = wave >> 1, wc = wave & 1;

  const int a_row0 = bm * BM;
  const int w_row0 = bn * BN;

  // ---- B staging (glds, 16B/lane): per instr covers 8 rows x 128B.
  // inverse-swizzle the SOURCE granule so linear LDS holds swizzled rows.
  const int b_r = lane >> 3;                 // 0..7 row within chunk
  const int b_g = (lane & 7) ^ b_r;          // source granule (involution)
  const u16* Wb = W + (size_t)(w_row0 + wave * 32 + b_r) * K + b_g * 8;
  const int sb_wbase = wave * 2048;          // u16: 4 chunks x 512

  // ---- A staging (reg): per instr j covers 4 rows x 256B f32 (coalesced).
  const int a_r = lane >> 4;                 // 0..3
  const int a_c = lane & 15;                 // 4-f32 group
  const float* Ab = A + (size_t)(a_row0 + wave * 32 + a_r) * K + a_c * 4;

  f32x4 acc[4][4] = {};
  f32x4 av[8];

  auto stage_B = [&](int buf, int kt) {
#pragma unroll
    for (int i = 0; i < 4; ++i)
      __builtin_amdgcn_global_load_lds((gas_cptr)(Wb + (size_t)i * 8 * K + kt),
                                       (las_ptr)(sB + buf * BBUF + sb_wbase + i * 512),
                                       16, 0, 0);
  };
  auto load_A = [&](int kt) {
#pragma unroll
    for (int j = 0; j < 8; ++j)
      av[j] = *(const f32x4*)(Ab + (size_t)j * 4 * K + kt);
  };
  auto write_A = [&](int buf) {
#pragma unroll
    for (int j = 0; j < 8; ++j) {
      const int row = wave * 32 + j * 4 + a_r;
      const int g = (a_c >> 1) ^ (row & 7);
      bf16x4 b;
      b[0] = (__bf16)av[j][0]; b[1] = (__bf16)av[j][1];
      b[2] = (__bf16)av[j][2]; b[3] = (__bf16)av[j][3];
      *(bf16x4*)&sA[buf * ABUF + row * 64 + g * 8 + (a_c & 1) * 4] = b;
    }
  };
  auto compute = [&](int buf) {
    const int fr = lane & 15;
    const int hi = lane >> 4;
#pragma unroll
    for (int ks = 0; ks < 2; ++ks) {
      bf16x8 af[4], bfr[4];
#pragma unroll
      for (int m = 0; m < 4; ++m) {
        const int row = wr * 64 + m * 16 + fr;
        const int g = (ks * 4 + hi) ^ (row & 7);
        af[m] = *(const bf16x8*)&sA[buf * ABUF + row * 64 + g * 8];
      }
#pragma unroll
      for (int n = 0; n < 4; ++n) {
        const int row = wc * 64 + n * 16 + fr;
        const int g = (ks * 4 + hi) ^ (row & 7);
        bfr[n] = *(const bf16x8*)&sB[buf * BBUF + row * 64 + g * 8];
      }
#pragma unroll
      for (int m = 0; m < 4; ++m)
#pragma unroll
        for (int n = 0; n < 4; ++n)
          acc[m][n] = __builtin_amdgcn_mfma_f32_16x16x32_bf16(af[m], bfr[n], acc[m][n], 0, 0, 0);
    }
  };

  // prologue
  stage_B(0, 0);
  load_A(0);
  write_A(0);
  __syncthreads();

  const int NK = K >> 6;
  int buf = 0;
  for (int t = 0; t < NK; ++t) {
    const int nxt = buf ^ 1;
    if (t + 1 < NK) {           // issue next-tile loads BEFORE compute
      stage_B(nxt, (t + 1) * BK);
      load_A((t + 1) * BK);
    }
    compute(buf);
    if (t + 1 < NK) write_A(nxt);  // write-late (T14): loads had MFMA time to land
    if (t + 1 < NK) __syncthreads();
    buf = nxt;
  }

  // epilogue: C/D layout col = lane&15, row = (lane>>4)*4 + reg  [m89-verified]
  const int fr = lane & 15;
  const int q = (lane >> 4) * 4;
#pragma unroll
  for (int m = 0; m < 4; ++m) {
#pragma unroll
    for (int j = 0; j < 4; ++j) {
      const size_t gr = (size_t)(a_row0 + wr * 64 + m * 16 + q + j);
      const size_t rowoff = gr * (size_t)N;
#pragma unroll
      for (int n = 0; n < 4; ++n) {
        const int gc = w_row0 + wc * 64 + n * 16 + fr;
        float v = acc[m][n][j];
        if (bias) v += bias[gc];
        if (R) v += R[rowoff + gc];
        if (OUT_BF16) ((u16*)Optr)[rowoff + gc] = f2bf(v);
        else          ((float*)Optr)[rowoff + gc] = v;
      }
    }
  }
}

// Row LayerNorm over D=1024 (f32 in/out, in-place safe), one wave per row.
__global__ __launch_bounds__(256) void ln_kernel(
    const float* Y, const float* __restrict__ g, const float* __restrict__ bta,
    float* Outp)
{
  const int wave = threadIdx.x >> 6, lane = threadIdx.x & 63;
  const size_t row = (size_t)blockIdx.x * 4 + wave;
  const float* y = Y + row * D_DIM + lane * 16;
  f32x4 v[4];
#pragma unroll
  for (int i = 0; i < 4; ++i) v[i] = *(const f32x4*)(y + i * 4);
  float s = 0.f, ss = 0.f;
#pragma unroll
  for (int i = 0; i < 4; ++i)
#pragma unroll
    for (int t = 0; t < 4; ++t) { float x = v[i][t]; s += x; ss += x * x; }
#pragma unroll
  for (int off = 32; off > 0; off >>= 1) {
    s += __shfl_xor(s, off, 64);
    ss += __shfl_xor(ss, off, 64);
  }
  const float mean = s * (1.f / 1024.f);
  const float var = ss * (1.f / 1024.f) - mean * mean;
  const float rstd = rsqrtf(var + 1e-5f);
  const int c0 = lane * 16;
  float* o = Outp + row * D_DIM + c0;
#pragma unroll
  for (int i = 0; i < 4; ++i) {
    f32x4 gg = *(const f32x4*)(g + c0 + i * 4);
    f32x4 bb = *(const f32x4*)(bta + c0 + i * 4);
    f32x4 ov;
#pragma unroll
    for (int t = 0; t < 4; ++t) ov[t] = (v[i][t] - mean) * rstd * gg[t] + bb[t];
    *(f32x4*)(o + i * 4) = ov;
  }
}

struct Ptr4 { const float* s[4]; u16* d[4]; };

// 1024x1024 transpose, f32 -> bf16, batched over z=0..3
__global__ __launch_bounds__(256) void transpose_kernel(Ptr4 p) {
  __shared__ float tile[32][33];
  const int z = blockIdx.z;
  const float* src = p.s[z];
  u16* dst = p.d[z];
  const int tx = threadIdx.x & 31, ty = threadIdx.x >> 5;
  const int gx = blockIdx.x * 32, gy = blockIdx.y * 32;
#pragma unroll
  for (int i = 0; i < 4; ++i) {
    const int r = ty + i * 8;
    tile[r][tx] = src[(size_t)(gy + r) * D_DIM + gx + tx];
  }
  __syncthreads();
#pragma unroll
  for (int i = 0; i < 4; ++i) {
    const int r = ty + i * 8;
    dst[(size_t)(gx + r) * D_DIM + gy + tx] = f2bf(tile[tx][r]);
  }
}

struct BiasArgs { const float* wout[4]; const float* bin[4]; const float* bout[4]; };

// cb[z][i] = sum_j w_out[i][j]*bv[j] + b_out[i]   (f32)
__global__ __launch_bounds__(256) void bias_kernel(BiasArgs p, float* cb) {
  const int z = blockIdx.z;
  const int i = blockIdx.x * 256 + threadIdx.x;
  const float* wrow = p.wout[z] + (size_t)i * D_DIM;
  const float* bv = p.bin[z] + 2 * D_DIM;
  float s = 0.f;
  for (int j = 0; j < D_DIM; j += 4) {
    f32x4 w4 = *(const f32x4*)&wrow[j];
    f32x4 b4 = *(const f32x4*)&bv[j];
#pragma unroll
    for (int t = 0; t < 4; ++t) s += w4[t] * b4[t];
  }
  cb[(size_t)z * D_DIM + i] = s + p.bout[z][i];
}

extern "C" void kernel_launch(void* const* d_in, const int* in_sizes, int n_in,
                              void* d_out, int out_size, void* d_ws, size_t ws_size,
                              hipStream_t stream) {
  (void)in_sizes; (void)n_in; (void)out_size; (void)ws_size;
  const size_t BD = (size_t)B_ROWS * D_DIM;
  const size_t DD = (size_t)D_DIM * D_DIM;

  const float* feat_local = (const float*)d_in[0];
  const float* feat_tact  = (const float*)d_in[1];
  const float* feat_strat = (const float*)d_in[2];
  // order per setup_inputs: [l2t, t2s, s2t, t2l] x (w_in, b_in, w_out, b_out)
  const float* w_in[4]  = {(const float*)d_in[3],  (const float*)d_in[7],  (const float*)d_in[11], (const float*)d_in[15]};
  const float* b_in[4]  = {(const float*)d_in[4],  (const float*)d_in[8],  (const float*)d_in[12], (const float*)d_in[16]};
  const float* w_out[4] = {(const float*)d_in[5],  (const float*)d_in[9],  (const float*)d_in[13], (const float*)d_in[17]};
  const float* b_out[4] = {(const float*)d_in[6],  (const float*)d_in[10], (const float*)d_in[14], (const float*)d_in[18]};
  const float* ln_g[3] = {(const float*)d_in[19], (const float*)d_in[21], (const float*)d_in[23]};
  const float* ln_b[3] = {(const float*)d_in[20], (const float*)d_in[22], (const float*)d_in[24]};

  u16* wvT = (u16*)d_ws;               // 4*DD bf16 = 8 MB
  u16* Wc  = wvT + 4 * DD;             // 4*DD bf16 = 8 MB
  float* cb = (float*)(Wc + 4 * DD);   // 4*1024 f32

  float* out = (float*)d_out;
  float* o_loc = out;            // chunk 0: loc
  float* o_tac = out + BD;       // chunk 1: tac (intermediate tacA, then final)
  float* o_str = out + 2 * BD;   // chunk 2: strat

  // 1. wvT_z = (w_in_z[2D:,:])^T as bf16
  Ptr4 tp;
  for (int z = 0; z < 4; ++z) { tp.s[z] = w_in[z] + 2 * DD; tp.d[z] = wvT + z * DD; }
  hipLaunchKernelGGL(transpose_kernel, dim3(32, 32, 4), dim3(256), 0, stream, tp);

  // 2. combined bias c = w_out*bv + b_out (f32)
  BiasArgs ba;
  for (int z = 0; z < 4; ++z) { ba.wout[z] = w_out[z]; ba.bin[z] = b_in[z]; ba.bout[z] = b_out[z]; }
  hipLaunchKernelGGL(bias_kernel, dim3(4, 1, 4), dim3(256), 0, stream, ba, cb);

  // 3. Wc_z = w_out_z(f32) @ wvT_z(bf16)^T -> bf16
  for (int z = 0; z < 4; ++z)
    hipLaunchKernelGGL((gemm_af32_bt<1>), dim3(8, 8), dim3(256), 0, stream,
                       w_out[z], wvT + z * DD, (const float*)nullptr, (const float*)nullptr,
                       (void*)(Wc + z * DD), 1024, 1024, 1024);

  // 4. S1: y1 = local @ Wc0^T + c0 + tactical -> chunk1; tacA = LN1(y1) in-place
  hipLaunchKernelGGL((gemm_af32_bt<0>), dim3(8, 512), dim3(256), 0, stream,
                     feat_local, Wc + 0 * DD, cb + 0, feat_tact, (void*)o_tac, B_ROWS, D_DIM, D_DIM);
  hipLaunchKernelGGL(ln_kernel, dim3(B_ROWS / 4), dim3(256), 0, stream, o_tac, ln_g[0], ln_b[0], o_tac);

  // 5. S2: y2 = tacA @ Wc1^T + c1 + strategic -> chunk2; strat = LN2(y2) in-place
  hipLaunchKernelGGL((gemm_af32_bt<0>), dim3(8, 512), dim3(256), 0, stream,
                     o_tac, Wc + 1 * DD, cb + 1024, feat_strat, (void*)o_str, B_ROWS, D_DIM, D_DIM);
  hipLaunchKernelGGL(ln_kernel, dim3(B_ROWS / 4), dim3(256), 0, stream, o_str, ln_g[1], ln_b[1], o_str);

  // 6. S3: y3 = strat @ Wc2^T + c2 + tacA -> chunk1 (elementwise in-place residual); tacB = LN3(y3)
  hipLaunchKernelGGL((gemm_af32_bt<0>), dim3(8, 512), dim3(256), 0, stream,
                     o_str, Wc + 2 * DD, cb + 2048, o_tac, (void*)o_tac, B_ROWS, D_DIM, D_DIM);
  hipLaunchKernelGGL(ln_kernel, dim3(B_ROWS / 4), dim3(256), 0, stream, o_tac, ln_g[2], ln_b[2], o_tac);

  // 7. S4: loc = local + tacB @ Wc3^T + c3 -> chunk0 (no LN)
  hipLaunchKernelGGL((gemm_af32_bt<0>), dim3(8, 512), dim3(256), 0, stream,
                     o_tac, Wc + 3 * DD, cb + 3072, feat_local, (void*)o_loc, B_ROWS, D_DIM, D_DIM);
}

// Round 4
// 2335.950 us; speedup vs baseline: 1.2098x; 1.2098x over previous
//
#include <hip/hip_runtime.h>

#define D_DIM 1024
#define B_ROWS 65536

typedef unsigned short u16;
typedef __attribute__((ext_vector_type(8))) __bf16 bf16x8;
typedef __attribute__((ext_vector_type(4))) float f32x4;
typedef __attribute__((ext_vector_type(8))) unsigned short u16x8;

typedef const __attribute__((address_space(1))) void* gas_cptr;
typedef __attribute__((address_space(3))) void* las_ptr;

__device__ __forceinline__ u16 f2bf(float f) {
  union { float fv; unsigned int i; } v; v.fv = f;
  return (u16)((v.i + 0x7FFFu + ((v.i >> 16) & 1u)) >> 16);
}
__device__ __forceinline__ float bf2f(u16 u) {
  union { unsigned int i; float f; } v; v.i = ((unsigned int)u) << 16; return v.f;
}

// ---------------- GEMM: C = A(bf16) @ W(bf16)^T (+bias) (+R) ----------------
// m97-faithful: 128x128 tile, BK=32, 4 waves (2x2), 16 KB LDS single-buffered,
// global_load_lds w16 for both operands, 2-barrier K-loop, linear LDS.
#define BM 128
#define BN 128
#define BK 32

template <int RESID, int OUTM>   // RESID: 0 none, 1 f32, 2 bf16 ; OUTM: 1 f32, 2 bf16
__global__ __launch_bounds__(256) void gemm_bf16(
    const u16* __restrict__ A, const u16* __restrict__ W,
    const float* __restrict__ bias, const void* Rp, void* Optr,
    int M, int N, int K)
{
  __shared__ __align__(16) u16 sA[BM * BK];  // 8 KB
  __shared__ __align__(16) u16 sB[BN * BK];  // 8 KB

  // XCD-aware bijective swizzle (all launches have nwg % 8 == 0)
  const int nbx = gridDim.x;
  const int nwg = nbx * gridDim.y;
  const int orig = blockIdx.y * nbx + blockIdx.x;
  const int cpx = nwg >> 3;
  const int swz = ((nwg & 7) == 0) ? ((orig & 7) * cpx + (orig >> 3)) : orig;
  const int bm = swz / nbx, bn = swz % nbx;

  const int tid = threadIdx.x;
  const int wave = tid >> 6;
  const int lane = tid & 63;
  const int wr = wave >> 1, wc = wave & 1;

  const int a_row0 = bm * BM;
  const int w_row0 = bn * BN;

  // staging: per wave, per operand: 2 glds covering 16 rows x 64 B each.
  const int st_r = lane >> 2;        // 0..15
  const int st_c = (lane & 3) * 8;   // 8 bf16 = 16 B
  const u16* Ab = A + (size_t)(a_row0 + wave * 32 + st_r) * K + st_c;
  const u16* Wb = W + (size_t)(w_row0 + wave * 32 + st_r) * K + st_c;

  f32x4 acc[4][4] = {};

  for (int kt = 0; kt < K; kt += BK) {
#pragma unroll
    for (int i = 0; i < 2; ++i) {
      __builtin_amdgcn_global_load_lds((gas_cptr)(Ab + (size_t)i * 16 * K + kt),
                                       (las_ptr)(sA + (wave * 2 + i) * 512), 16, 0, 0);
      __builtin_amdgcn_global_load_lds((gas_cptr)(Wb + (size_t)i * 16 * K + kt),
                                       (las_ptr)(sB + (wave * 2 + i) * 512), 16, 0, 0);
    }
    __syncthreads();

    const int fr = lane & 15;
    const int fk = (lane >> 4) * 8;
    bf16x8 af[4], bfr[4];
#pragma unroll
    for (int m = 0; m < 4; ++m)
      af[m] = *(const bf16x8*)&sA[(wr * 64 + m * 16 + fr) * BK + fk];
#pragma unroll
    for (int n = 0; n < 4; ++n)
      bfr[n] = *(const bf16x8*)&sB[(wc * 64 + n * 16 + fr) * BK + fk];
#pragma unroll
    for (int m = 0; m < 4; ++m)
#pragma unroll
      for (int n = 0; n < 4; ++n)
        acc[m][n] = __builtin_amdgcn_mfma_f32_16x16x32_bf16(af[m], bfr[n], acc[m][n], 0, 0, 0);
    __syncthreads();
  }

  // epilogue: C/D layout col = lane&15, row = (lane>>4)*4 + reg  [m89-verified]
  const float* Rf = (const float*)Rp;
  const u16*   Rb = (const u16*)Rp;
  const int fr = lane & 15;
  const int q = (lane >> 4) * 4;
#pragma unroll
  for (int m = 0; m < 4; ++m) {
#pragma unroll
    for (int j = 0; j < 4; ++j) {
      const size_t rowoff = (size_t)(a_row0 + wr * 64 + m * 16 + q + j) * (size_t)N;
#pragma unroll
      for (int n = 0; n < 4; ++n) {
        const int gc = w_row0 + wc * 64 + n * 16 + fr;
        float v = acc[m][n][j];
        if (bias) v += bias[gc];
        if (RESID == 1) v += Rf[rowoff + gc];
        if (RESID == 2) v += bf2f(Rb[rowoff + gc]);
        if (OUTM == 1) ((float*)Optr)[rowoff + gc] = v;
        else           ((u16*)Optr)[rowoff + gc] = f2bf(v);
      }
    }
  }
}

// ---------------- LayerNorm: bf16 in, optional f32 out + bf16 side-copy -----
// one wave per row; in-place safe (ObfP may == Y).
template <int OUTF32, int OUTBF16>
__global__ __launch_bounds__(256) void ln_kernel(
    const u16* Y, const float* __restrict__ g, const float* __restrict__ bta,
    float* Of32, u16* Obf)
{
  const int wave = threadIdx.x >> 6, lane = threadIdx.x & 63;
  const size_t row = (size_t)blockIdx.x * 4 + wave;
  const u16* y = Y + row * D_DIM + lane * 16;
  u16x8 v0 = *(const u16x8*)y;
  u16x8 v1 = *(const u16x8*)(y + 8);
  float x[16];
#pragma unroll
  for (int i = 0; i < 8; ++i) { x[i] = bf2f(v0[i]); x[8 + i] = bf2f(v1[i]); }
  float s = 0.f, ss = 0.f;
#pragma unroll
  for (int i = 0; i < 16; ++i) { s += x[i]; ss += x[i] * x[i]; }
#pragma unroll
  for (int off = 32; off > 0; off >>= 1) {
    s += __shfl_xor(s, off, 64);
    ss += __shfl_xor(ss, off, 64);
  }
  const float mean = s * (1.f / 1024.f);
  const float var = ss * (1.f / 1024.f) - mean * mean;
  const float rstd = rsqrtf(var + 1e-5f);
  const int c0 = lane * 16;
  float o[16];
#pragma unroll
  for (int i = 0; i < 16; ++i)
    o[i] = (x[i] - mean) * rstd * g[c0 + i] + bta[c0 + i];
  if (OUTF32) {
    float* p = Of32 + row * D_DIM + c0;
#pragma unroll
    for (int i = 0; i < 4; ++i) {
      f32x4 ov; ov[0] = o[i*4]; ov[1] = o[i*4+1]; ov[2] = o[i*4+2]; ov[3] = o[i*4+3];
      *(f32x4*)(p + i * 4) = ov;
    }
  }
  if (OUTBF16) {
    u16x8 b0, b1;
#pragma unroll
    for (int i = 0; i < 8; ++i) { b0[i] = f2bf(o[i]); b1[i] = f2bf(o[8 + i]); }
    u16* p = Obf + row * D_DIM + c0;
    *(u16x8*)p = b0;
    *(u16x8*)(p + 8) = b1;
  }
}

// ---------------- f32 -> bf16 conversion (grid-stride, 8/thread) -----------
__global__ __launch_bounds__(256) void cvt_kernel(const float* __restrict__ src,
                                                  u16* __restrict__ dst, size_t n)
{
  const size_t stride = (size_t)gridDim.x * 256 * 8;
  for (size_t i = ((size_t)blockIdx.x * 256 + threadIdx.x) * 8; i < n; i += stride) {
    f32x4 a = *(const f32x4*)(src + i);
    f32x4 b = *(const f32x4*)(src + i + 4);
    u16x8 o;
#pragma unroll
    for (int t = 0; t < 4; ++t) { o[t] = f2bf(a[t]); o[t + 4] = f2bf(b[t]); }
    *(u16x8*)(dst + i) = o;
  }
}

struct Ptr4 { const float* s[4]; u16* d[4]; };

// 1024x1024 transpose, f32 -> bf16, batched over z=0..3
__global__ __launch_bounds__(256) void transpose_kernel(Ptr4 p) {
  __shared__ float tile[32][33];
  const int z = blockIdx.z;
  const float* src = p.s[z];
  u16* dst = p.d[z];
  const int tx = threadIdx.x & 31, ty = threadIdx.x >> 5;
  const int gx = blockIdx.x * 32, gy = blockIdx.y * 32;
#pragma unroll
  for (int i = 0; i < 4; ++i) {
    const int r = ty + i * 8;
    tile[r][tx] = src[(size_t)(gy + r) * D_DIM + gx + tx];
  }
  __syncthreads();
#pragma unroll
  for (int i = 0; i < 4; ++i) {
    const int r = ty + i * 8;
    dst[(size_t)(gx + r) * D_DIM + gy + tx] = f2bf(tile[tx][r]);
  }
}

struct BiasArgs { const float* wout[4]; const float* bin[4]; const float* bout[4]; };

// cb[z][i] = sum_j w_out[i][j]*bv[j] + b_out[i]   (f32)
__global__ __launch_bounds__(256) void bias_kernel(BiasArgs p, float* cb) {
  const int z = blockIdx.z;
  const int i = blockIdx.x * 256 + threadIdx.x;
  const float* wrow = p.wout[z] + (size_t)i * D_DIM;
  const float* bv = p.bin[z] + 2 * D_DIM;
  float s = 0.f;
  for (int j = 0; j < D_DIM; j += 4) {
    f32x4 w4 = *(const f32x4*)&wrow[j];
    f32x4 b4 = *(const f32x4*)&bv[j];
#pragma unroll
    for (int t = 0; t < 4; ++t) s += w4[t] * b4[t];
  }
  cb[(size_t)z * D_DIM + i] = s + p.bout[z][i];
}

extern "C" void kernel_launch(void* const* d_in, const int* in_sizes, int n_in,
                              void* d_out, int out_size, void* d_ws, size_t ws_size,
                              hipStream_t stream) {
  (void)in_sizes; (void)n_in; (void)out_size; (void)ws_size;
  const size_t BD = (size_t)B_ROWS * D_DIM;
  const size_t DD = (size_t)D_DIM * D_DIM;

  const float* feat_local = (const float*)d_in[0];
  const float* feat_tact  = (const float*)d_in[1];
  const float* feat_strat = (const float*)d_in[2];
  // order per setup_inputs: [l2t, t2s, s2t, t2l] x (w_in, b_in, w_out, b_out)
  const float* w_in[4]  = {(const float*)d_in[3],  (const float*)d_in[7],  (const float*)d_in[11], (const float*)d_in[15]};
  const float* b_in[4]  = {(const float*)d_in[4],  (const float*)d_in[8],  (const float*)d_in[12], (const float*)d_in[16]};
  const float* w_out[4] = {(const float*)d_in[5],  (const float*)d_in[9],  (const float*)d_in[13], (const float*)d_in[17]};
  const float* b_out[4] = {(const float*)d_in[6],  (const float*)d_in[10], (const float*)d_in[14], (const float*)d_in[18]};
  const float* ln_g[3] = {(const float*)d_in[19], (const float*)d_in[21], (const float*)d_in[23]};
  const float* ln_b[3] = {(const float*)d_in[20], (const float*)d_in[22], (const float*)d_in[24]};

  // workspace layout (u16 units): two 128 MiB bf16 stream buffers + weights
  u16* buf0 = (u16*)d_ws;          // lbf -> y2/strat_bf
  u16* buf1 = buf0 + BD;           // y1/tacA_bf -> y3/tacB_bf
  u16* wvT  = buf1 + BD;           // 4*DD
  u16* wobf = wvT + 4 * DD;        // 4*DD
  u16* Wc   = wobf + 4 * DD;       // 4*DD
  float* cb = (float*)(Wc + 4 * DD);

  float* out = (float*)d_out;
  float* o_loc = out;
  float* o_tac = out + BD;
  float* o_str = out + 2 * BD;

  // 0. conversions: local -> bf16 (buf0), w_out -> bf16
  hipLaunchKernelGGL(cvt_kernel, dim3(2048), dim3(256), 0, stream, feat_local, buf0, BD);
  for (int z = 0; z < 4; ++z)
    hipLaunchKernelGGL(cvt_kernel, dim3(256), dim3(256), 0, stream, w_out[z], wobf + z * DD, DD);

  // 1. wvT_z = (w_in_z[2D:,:])^T as bf16
  Ptr4 tp;
  for (int z = 0; z < 4; ++z) { tp.s[z] = w_in[z] + 2 * DD; tp.d[z] = wvT + z * DD; }
  hipLaunchKernelGGL(transpose_kernel, dim3(32, 32, 4), dim3(256), 0, stream, tp);

  // 2. combined bias c = w_out*bv + b_out (f32)
  BiasArgs ba;
  for (int z = 0; z < 4; ++z) { ba.wout[z] = w_out[z]; ba.bin[z] = b_in[z]; ba.bout[z] = b_out[z]; }
  hipLaunchKernelGGL(bias_kernel, dim3(4, 1, 4), dim3(256), 0, stream, ba, cb);

  // 3. Wc_z = w_out_z(bf16) @ wvT_z(bf16)^T -> bf16
  for (int z = 0; z < 4; ++z)
    hipLaunchKernelGGL((gemm_bf16<0, 2>), dim3(8, 8), dim3(256), 0, stream,
                       wobf + z * DD, wvT + z * DD, (const float*)nullptr,
                       (const void*)nullptr, (void*)(Wc + z * DD), 1024, 1024, 1024);

  // 4. S1: y1 = lbf @ Wc0^T + c0 + tact(f32) -> buf1 (bf16); tacA = LN1(y1) in-place bf16
  hipLaunchKernelGGL((gemm_bf16<1, 2>), dim3(8, 512), dim3(256), 0, stream,
                     buf0, Wc + 0 * DD, cb + 0, (const void*)feat_tact, (void*)buf1,
                     B_ROWS, D_DIM, D_DIM);
  hipLaunchKernelGGL((ln_kernel<0, 1>), dim3(B_ROWS / 4), dim3(256), 0, stream,
                     buf1, ln_g[0], ln_b[0], (float*)nullptr, buf1);

  // 5. S2: y2 = tacA @ Wc1^T + c1 + strat(f32) -> buf0 (bf16);
  //    LN2 -> strat f32 (final) + strat_bf in-place
  hipLaunchKernelGGL((gemm_bf16<1, 2>), dim3(8, 512), dim3(256), 0, stream,
                     buf1, Wc + 1 * DD, cb + 1024, (const void*)feat_strat, (void*)buf0,
                     B_ROWS, D_DIM, D_DIM);
  hipLaunchKernelGGL((ln_kernel<1, 1>), dim3(B_ROWS / 4), dim3(256), 0, stream,
                     buf0, ln_g[1], ln_b[1], o_str, buf0);

  // 6. S3: y3 = strat_bf @ Wc2^T + c2 + tacA(bf16, aliases O) -> buf1 (bf16);
  //    LN3 -> tac f32 (final) + tacB_bf in-place
  hipLaunchKernelGGL((gemm_bf16<2, 2>), dim3(8, 512), dim3(256), 0, stream,
                     buf0, Wc + 2 * DD, cb + 2048, (const void*)buf1, (void*)buf1,
                     B_ROWS, D_DIM, D_DIM);
  hipLaunchKernelGGL((ln_kernel<1, 1>), dim3(B_ROWS / 4), dim3(256), 0, stream,
                     buf1, ln_g[2], ln_b[2], o_tac, buf1);

  // 7. S4: loc = local(f32) + tacB @ Wc3^T + c3 -> chunk0 f32 (no LN)
  hipLaunchKernelGGL((gemm_bf16<1, 1>), dim3(8, 512), dim3(256), 0, stream,
                     buf1, Wc + 3 * DD, cb + 3072, (const void*)feat_local, (void*)o_loc,
                     B_ROWS, D_DIM, D_DIM);
}